// Round 1
// baseline (537.460 us; speedup 1.0000x reference)
//
#include <hip/hip_runtime.h>
#include <hip/hip_bf16.h>
#include <stdint.h>

typedef _Float16 half_t;
typedef __attribute__((ext_vector_type(8))) _Float16 half8;
typedef __attribute__((ext_vector_type(4))) _Float16 half4v;
typedef __attribute__((ext_vector_type(4))) float float4v;
typedef unsigned long long u64;

#define D_DIM 768
#define K_CENT 1024
#define M_TOTAL 65536
#define BM 128
#define BN 128
#define BK 64
#define NCHUNK 12   /* 768/64 */
#define NTN 8       /* 1024/128 */

/* ws layout (bytes):
   [0, 1.5MB)        Chi: pre-swizzled f16 hi tiles, [n_tile][chunk][16KB]
   [1.5MB, 3MB)      Clo: f16 lo tiles, same layout
   [3MB, 3MB+4KB)    c2[1024] fp32
   [3MB+8KB, +4MB)   partial u64 [65536][8]                                  */
#define CLO_OFF   (NTN * NCHUNK * 16384u)      /* 1.5 MB */
#define C2_OFF    (2u * CLO_OFF)               /* 3 MB */
#define PART_OFF  (C2_OFF + 8192u)

// XOR swizzle: breaks the 128B-row-stride 16-way bank conflict on ds_read_b128
// (lanes 0..15 read 16 different rows at the same k). rows r and r+8 alias -> 2-way = free.
__device__ __forceinline__ uint32_t swz(uint32_t row, uint32_t kbyte) {
  return (row * 128u + kbyte) ^ ((row & 7u) << 4);
}

__device__ __forceinline__ void gll16(const void* g, void* l) {
  __builtin_amdgcn_global_load_lds((const __attribute__((address_space(1))) void*)g,
                                   (__attribute__((address_space(3))) void*)l,
                                   16, 0, 0);
}

// ---------------- kernel 1: centroid split + c2 ----------------
__global__ __launch_bounds__(256) void prep_centroids(const float* __restrict__ cent,
                                                      uint8_t* __restrict__ ws) {
  const int n = blockIdx.x;            // centroid index 0..1023
  const int nt = n >> 7, row = n & 127;
  float ss = 0.f;
  for (int d = threadIdx.x; d < D_DIM; d += 256) {
    float a = cent[n * D_DIM + d];
    ss += a * a;
    half_t hi = (half_t)a;
    half_t lo = (half_t)(a - (float)hi);
    int chunk = d >> 6, k = d & 63;
    uint32_t off = ((uint32_t)(nt * NCHUNK + chunk) << 14) + swz((uint32_t)row, (uint32_t)k * 2u);
    *(half_t*)(ws + off) = hi;
    *(half_t*)(ws + CLO_OFF + off) = lo;
  }
  // block reduce ss -> c2[n]
  for (int s = 32; s > 0; s >>= 1) ss += __shfl_down(ss, s, 64);
  __shared__ float red[4];
  if ((threadIdx.x & 63) == 0) red[threadIdx.x >> 6] = ss;
  __syncthreads();
  if (threadIdx.x == 0) {
    float* c2 = (float*)(ws + C2_OFF);
    c2[n] = red[0] + red[1] + red[2] + red[3];
  }
}

// ---------------- kernel 2: fused split-f16 GEMM + per-tile argmin ----------------
__global__ __launch_bounds__(256, 2) void cluster_gemm(const float* __restrict__ X,
                                                       const uint8_t* __restrict__ wsro,
                                                       u64* __restrict__ partial) {
  __shared__ uint8_t smem[65536];
  uint8_t* Ahi = smem;
  uint8_t* Alo = smem + 16384;
  uint8_t* Bhi = smem + 32768;
  uint8_t* Blo = smem + 49152;

  // bijective XCD swizzle: XCD x gets contiguous logical range -> the 8 n-tiles
  // of an m-tile are consecutive on one XCD (A-tile L2 reuse).
  const int bid = blockIdx.x;
  const int L = (bid & 7) * 512 + (bid >> 3);
  const int m_tile = L >> 3;
  const int n_tile = L & 7;
  const int m0 = m_tile * BM;

  const int tid = threadIdx.x;
  const int lane = tid & 63, w = tid >> 6;
  const int wm = w >> 1, wn = w & 1;

  const float* c2p = (const float*)(wsro + C2_OFF);
  const int ncol = n_tile * 128 + wn * 64 + (lane & 15);
  float c2v[4];
#pragma unroll
  for (int n = 0; n < 4; ++n) c2v[n] = c2p[ncol + n * 16];

  float4v acc[4][4];
#pragma unroll
  for (int m = 0; m < 4; ++m)
#pragma unroll
    for (int n = 0; n < 4; ++n) acc[m][n] = (float4v){0.f, 0.f, 0.f, 0.f};

  for (int ch = 0; ch < NCHUNK; ++ch) {
    __syncthreads();
    // ---- B: async global->LDS (pre-split, pre-swizzled in ws) ----
    {
      const uint8_t* srcHi = wsro + (((uint32_t)(n_tile * NCHUNK + ch)) << 14);
      const uint8_t* srcLo = srcHi + CLO_OFF;
      const uint32_t wo = (uint32_t)w << 12;
#pragma unroll
      for (int j = 0; j < 4; ++j) {
        uint32_t off = wo + (uint32_t)j * 1024u;
        gll16(srcHi + off + (lane << 4), Bhi + off);
        gll16(srcLo + off + (lane << 4), Blo + off);
      }
    }
    // ---- A: reg-stage fp32 -> hi/lo f16, swizzled ds_write ----
    {
      const int d0 = ch * BK;
#pragma unroll
      for (int i = 0; i < 8; ++i) {
        int f = tid + i * 256;
        int row = f >> 4, c4 = f & 15;
        float4v v = *(const float4v*)(X + (size_t)(m0 + row) * D_DIM + d0 + c4 * 4);
        half4v hi, lo;
#pragma unroll
        for (int jj = 0; jj < 4; ++jj) {
          half_t h = (half_t)v[jj];
          hi[jj] = h;
          lo[jj] = (half_t)(v[jj] - (float)h);
        }
        uint32_t a = swz((uint32_t)row, (uint32_t)c4 * 8u);
        *(half4v*)(Ahi + a) = hi;
        *(half4v*)(Alo + a) = lo;
      }
    }
    __syncthreads();
    // ---- compute: 3-term split product, 96 MFMA / wave / chunk ----
#pragma unroll
    for (int ks = 0; ks < 2; ++ks) {
      half8 ah[4], al[4], bh[4], bl[4];
      const uint32_t kb = (uint32_t)ks * 64u + (uint32_t)((lane >> 4) << 4);
#pragma unroll
      for (int m = 0; m < 4; ++m) {
        uint32_t row = (uint32_t)(wm * 64 + m * 16 + (lane & 15));
        uint32_t a = swz(row, kb);
        ah[m] = *(const half8*)(Ahi + a);
        al[m] = *(const half8*)(Alo + a);
      }
#pragma unroll
      for (int n = 0; n < 4; ++n) {
        uint32_t row = (uint32_t)(wn * 64 + n * 16 + (lane & 15));
        uint32_t a = swz(row, kb);
        bh[n] = *(const half8*)(Bhi + a);
        bl[n] = *(const half8*)(Blo + a);
      }
#pragma unroll
      for (int m = 0; m < 4; ++m)
#pragma unroll
        for (int n = 0; n < 4; ++n) {
          acc[m][n] = __builtin_amdgcn_mfma_f32_16x16x32_f16(ah[m], bh[n], acc[m][n], 0, 0, 0);
          acc[m][n] = __builtin_amdgcn_mfma_f32_16x16x32_f16(ah[m], bl[n], acc[m][n], 0, 0, 0);
          acc[m][n] = __builtin_amdgcn_mfma_f32_16x16x32_f16(al[m], bh[n], acc[m][n], 0, 0, 0);
        }
    }
  }

  // ---- epilogue: score = c2 - 2*dot ; per-row argmin over this n-tile ----
  __syncthreads();                       // LDS reads done; reuse smem as scratch
  u64* scratch = (u64*)smem;             // [128 rows][2 wn]
  const int g = lane >> 4;
#pragma unroll
  for (int m = 0; m < 4; ++m) {
#pragma unroll
    for (int r = 0; r < 4; ++r) {
      u64 key = ~0ull;
#pragma unroll
      for (int n = 0; n < 4; ++n) {
        float s = c2v[n] - 2.0f * acc[m][n][r];
        uint32_t ub = __float_as_uint(s);
        ub ^= (uint32_t)((int32_t)ub >> 31) | 0x80000000u;   // order-preserving flip
        u64 cand = ((u64)ub << 32) | (uint32_t)(ncol + n * 16);
        key = cand < key ? cand : key;
      }
#pragma unroll
      for (int d = 1; d < 16; d <<= 1) {
        u64 o = __shfl_xor(key, d, 64);
        key = o < key ? o : key;
      }
      if ((lane & 15) == 0) {
        int row = wm * 64 + m * 16 + g * 4 + r;
        scratch[row * 2 + wn] = key;
      }
    }
  }
  __syncthreads();
  if (tid < 128) {
    u64 k0 = scratch[tid * 2 + 0], k1 = scratch[tid * 2 + 1];
    partial[(size_t)(m0 + tid) * NTN + n_tile] = k0 < k1 ? k0 : k1;
  }
}

// ---------------- kernel 3: combine partials -> output ----------------
__global__ __launch_bounds__(256) void finalize(const u64* __restrict__ partial,
                                                const float* __restrict__ gates,
                                                const float* __restrict__ att,
                                                const int* __restrict__ ecp,
                                                float* __restrict__ out) {
  int r = blockIdx.x * 256 + threadIdx.x;
  const u64* p = partial + (size_t)r * NTN;
  u64 k = p[0];
#pragma unroll
  for (int j = 1; j < NTN; ++j) { u64 o = p[j]; k = o < k ? o : k; }
  int idx = (int)(uint32_t)k;
  out[r] = gates[r] * att[r] * ((idx == *ecp) ? 1.0f : 0.0f);
}

extern "C" void kernel_launch(void* const* d_in, const int* in_sizes, int n_in,
                              void* d_out, int out_size, void* d_ws, size_t ws_size,
                              hipStream_t stream) {
  const float* X     = (const float*)d_in[0];
  const float* gates = (const float*)d_in[1];
  const float* att   = (const float*)d_in[2];
  const float* cent  = (const float*)d_in[3];
  const int*   ec    = (const int*)d_in[4];
  uint8_t* ws = (uint8_t*)d_ws;
  float* out = (float*)d_out;
  u64* partial = (u64*)(ws + PART_OFF);

  prep_centroids<<<K_CENT, 256, 0, stream>>>(cent, ws);
  cluster_gemm<<<(M_TOTAL / BM) * NTN, 256, 0, stream>>>(X, ws, partial);
  finalize<<<M_TOTAL / 256, 256, 0, stream>>>(partial, gates, att, ec, out);
}

// Round 5
// 534.575 us; speedup vs baseline: 1.0054x; 1.0054x over previous
//
#include <hip/hip_runtime.h>
#include <hip/hip_bf16.h>
#include <stdint.h>

typedef _Float16 half_t;
typedef __attribute__((ext_vector_type(8))) _Float16 half8;
typedef __attribute__((ext_vector_type(4))) _Float16 half4v;
typedef __attribute__((ext_vector_type(4))) float float4v;
typedef unsigned long long u64;

#define D_DIM 768
#define K_CENT 1024
#define M_TOTAL 65536
#define BM 128
#define BN 128
#define BK 32
#define NCHUNK 24   /* 768/32 */
#define NTN 8       /* 1024/128 */

#define BPLANE 8192u   /* one hi or lo B plane per chunk: 128 rows x 64 B */

/* ws layout (bytes):
   [0, 1.5MB)        Chi: pre-swizzled f16 hi tiles, [n_tile][chunk(24)][8KB]
   [1.5MB, 3MB)      Clo: f16 lo tiles, same layout
   [3MB, 3MB+4KB)    c2[1024] fp32
   [3MB+8KB, +4MB)   partial u64 [65536][8]                                  */
#define CLO_OFF   (NTN * NCHUNK * BPLANE)      /* 1.5 MB */
#define C2_OFF    (2u * CLO_OFF)               /* 3 MB */
#define PART_OFF  (C2_OFF + 8192u)

// XOR swizzle for 64B row stride: rows r and r+8 alias (2-way = free); a wave's
// 16-rows-x-4-kslots ds_read_b128 pattern distributes uniformly over bank groups.
__device__ __forceinline__ uint32_t swz(uint32_t row, uint32_t kbyte) {
  return (row * 64u + kbyte) ^ (((row >> 1) & 3u) << 4);
}

__device__ __forceinline__ void gll16(const void* g, void* l) {
  __builtin_amdgcn_global_load_lds((const __attribute__((address_space(1))) void*)g,
                                   (__attribute__((address_space(3))) void*)l,
                                   16, 0, 0);
}

// ---------------- kernel 1: centroid split + c2 ----------------
__global__ __launch_bounds__(256) void prep_centroids(const float* __restrict__ cent,
                                                      uint8_t* __restrict__ ws) {
  const int n = blockIdx.x;            // centroid index 0..1023
  const int nt = n >> 7, row = n & 127;
  float ss = 0.f;
  for (int d = threadIdx.x; d < D_DIM; d += 256) {
    float a = cent[n * D_DIM + d];
    ss += a * a;
    half_t hi = (half_t)a;
    half_t lo = (half_t)(a - (float)hi);
    int chunk = d >> 5, k = d & 31;
    uint32_t off = (uint32_t)(nt * NCHUNK + chunk) * BPLANE + swz((uint32_t)row, (uint32_t)k * 2u);
    *(half_t*)(ws + off) = hi;
    *(half_t*)(ws + CLO_OFF + off) = lo;
  }
  for (int s = 32; s > 0; s >>= 1) ss += __shfl_down(ss, s, 64);
  __shared__ float red[4];
  if ((threadIdx.x & 63) == 0) red[threadIdx.x >> 6] = ss;
  __syncthreads();
  if (threadIdx.x == 0) {
    float* c2 = (float*)(ws + C2_OFF);
    c2[n] = red[0] + red[1] + red[2] + red[3];
  }
}

// ---------------- kernel 2: pipelined split-f16 GEMM + per-tile argmin ----------------
// Double-buffered (2 x 32KB): per buffer  Ahi[8K] | Alo[8K] | Bhi[8K] | Blo[8K].
// Per chunk: issue next B gll + next A global loads BEFORE the MFMA cluster;
// convert+ds_write A after MFMA; ONE barrier per chunk.
__global__ __launch_bounds__(256, 2) void cluster_gemm(const float* __restrict__ X,
                                                       const uint8_t* __restrict__ wsro,
                                                       u64* __restrict__ partial) {
  __shared__ uint8_t smem[65536];

  // bijective XCD swizzle: XCD x gets contiguous logical L range; 8 consecutive
  // L values share one A m-tile (L2 reuse) and full B fits per-XCD L2.
  const int bid = blockIdx.x;
  const int L = (bid & 7) * 512 + (bid >> 3);
  const int m_tile = L >> 3;
  const int n_tile = L & 7;
  const int m0 = m_tile * BM;

  const int tid = threadIdx.x;
  const int lane = tid & 63, w = tid >> 6;
  const int wm = w >> 1, wn = w & 1;

  const float* c2p = (const float*)(wsro + C2_OFF);
  const int ncol = n_tile * 128 + wn * 64 + (lane & 15);
  float c2v[4];
#pragma unroll
  for (int n = 0; n < 4; ++n) c2v[n] = c2p[ncol + n * 16];

  float4v acc[4][4];
#pragma unroll
  for (int m = 0; m < 4; ++m)
#pragma unroll
    for (int n = 0; n < 4; ++n) acc[m][n] = (float4v){0.f, 0.f, 0.f, 0.f};

  const uint8_t* Bsrc = wsro + (uint32_t)(n_tile * NCHUNK) * BPLANE;
  const uint32_t wo = (uint32_t)w * 2048u;

  // ---- prologue: stage chunk 0 into buffer 0 ----
  {
#pragma unroll
    for (int j = 0; j < 2; ++j) {
      uint32_t off = wo + (uint32_t)j * 1024u;
      gll16(Bsrc + off + (lane << 4), smem + 16384u + off);
      gll16(Bsrc + CLO_OFF + off + (lane << 4), smem + 24576u + off);
    }
#pragma unroll
    for (int i = 0; i < 4; ++i) {
      int f = tid + i * 256;
      int row = f >> 3, c4 = f & 7;
      float4v v = *(const float4v*)(X + (size_t)(m0 + row) * D_DIM + c4 * 4);
      half4v hi, lo;
#pragma unroll
      for (int jj = 0; jj < 4; ++jj) {
        half_t h = (half_t)v[jj];
        hi[jj] = h;
        lo[jj] = (half_t)(v[jj] - (float)h);
      }
      uint32_t a = swz((uint32_t)row, (uint32_t)c4 * 8u);
      *(half4v*)(smem + a) = hi;
      *(half4v*)(smem + 8192u + a) = lo;
    }
    __syncthreads();
  }

  uint32_t co = 0;                       // current buffer byte offset (0 or 32768)
  for (int ch = 0; ch < NCHUNK; ++ch) {
    const uint32_t nco = co ^ 32768u;
    float4v apf[4];
    const bool pf = (ch + 1 < NCHUNK);
    // ---- issue next chunk's loads EARLY (latency hides under MFMA) ----
    if (pf) {
      const uint8_t* sh = Bsrc + (uint32_t)(ch + 1) * BPLANE;
#pragma unroll
      for (int j = 0; j < 2; ++j) {
        uint32_t off = wo + (uint32_t)j * 1024u;
        gll16(sh + off + (lane << 4), smem + nco + 16384u + off);
        gll16(sh + CLO_OFF + off + (lane << 4), smem + nco + 24576u + off);
      }
      const int d0 = (ch + 1) * BK;
#pragma unroll
      for (int i = 0; i < 4; ++i) {
        int f = tid + i * 256;
        int row = f >> 3, c4 = f & 7;
        apf[i] = *(const float4v*)(X + (size_t)(m0 + row) * D_DIM + d0 + c4 * 4);
      }
    }
    // ---- ds_read fragments from current buffer ----
    half8 ah[4], al[4], bh[4], bl[4];
    const uint32_t kb = (uint32_t)((lane >> 4) << 4);
#pragma unroll
    for (int m = 0; m < 4; ++m) {
      uint32_t a = co + swz((uint32_t)(wm * 64 + m * 16 + (lane & 15)), kb);
      ah[m] = *(const half8*)(smem + a);
      al[m] = *(const half8*)(smem + 8192u + a);
    }
#pragma unroll
    for (int n = 0; n < 4; ++n) {
      uint32_t a = co + swz((uint32_t)(wn * 64 + n * 16 + (lane & 15)), kb);
      bh[n] = *(const half8*)(smem + 16384u + a);
      bl[n] = *(const half8*)(smem + 24576u + a);
    }
    // ---- 48 MFMA: 3-term Dekker split (hh + hl + lh) ----
    __builtin_amdgcn_s_setprio(1);
#pragma unroll
    for (int m = 0; m < 4; ++m)
#pragma unroll
      for (int n = 0; n < 4; ++n) {
        acc[m][n] = __builtin_amdgcn_mfma_f32_16x16x32_f16(ah[m], bh[n], acc[m][n], 0, 0, 0);
        acc[m][n] = __builtin_amdgcn_mfma_f32_16x16x32_f16(ah[m], bl[n], acc[m][n], 0, 0, 0);
        acc[m][n] = __builtin_amdgcn_mfma_f32_16x16x32_f16(al[m], bh[n], acc[m][n], 0, 0, 0);
      }
    __builtin_amdgcn_s_setprio(0);
    // ---- convert + write next A tile (loads have had the MFMA block to land) ----
    if (pf) {
#pragma unroll
      for (int i = 0; i < 4; ++i) {
        int f = tid + i * 256;
        int row = f >> 3, c4 = f & 7;
        half4v hi, lo;
#pragma unroll
        for (int jj = 0; jj < 4; ++jj) {
          half_t h = (half_t)apf[i][jj];
          hi[jj] = h;
          lo[jj] = (half_t)(apf[i][jj] - (float)h);
        }
        uint32_t a = swz((uint32_t)row, (uint32_t)c4 * 8u);
        *(half4v*)(smem + nco + a) = hi;
        *(half4v*)(smem + nco + 8192u + a) = lo;
      }
    }
    __syncthreads();
    co = nco;
  }

  // ---- epilogue: score = c2 - 2*dot ; per-row argmin over this n-tile ----
  u64* scratch = (u64*)smem;             // safe: last loop iter ended with barrier
  const int g = lane >> 4;
#pragma unroll
  for (int m = 0; m < 4; ++m) {
#pragma unroll
    for (int r = 0; r < 4; ++r) {
      u64 key = ~0ull;
#pragma unroll
      for (int n = 0; n < 4; ++n) {
        float s = c2v[n] - 2.0f * acc[m][n][r];
        uint32_t ub = __float_as_uint(s);
        ub ^= (uint32_t)((int32_t)ub >> 31) | 0x80000000u;   // order-preserving flip
        u64 cand = ((u64)ub << 32) | (uint32_t)(ncol + n * 16);
        key = cand < key ? cand : key;
      }
#pragma unroll
      for (int d = 1; d < 16; d <<= 1) {
        u64 o = __shfl_xor(key, d, 64);
        key = o < key ? o : key;
      }
      if ((lane & 15) == 0) {
        int row = wm * 64 + m * 16 + g * 4 + r;
        scratch[row * 2 + wn] = key;
      }
    }
  }
  __syncthreads();
  if (tid < 128) {
    u64 k0 = scratch[tid * 2 + 0], k1 = scratch[tid * 2 + 1];
    partial[(size_t)(m0 + tid) * NTN + n_tile] = k0 < k1 ? k0 : k1;
  }
}

// ---------------- kernel 3: combine partials -> output ----------------
__global__ __launch_bounds__(256) void finalize(const u64* __restrict__ partial,
                                                const float* __restrict__ gates,
                                                const float* __restrict__ att,
                                                const int* __restrict__ ecp,
                                                float* __restrict__ out) {
  int r = blockIdx.x * 256 + threadIdx.x;
  const u64* p = partial + (size_t)r * NTN;
  u64 k = p[0];
#pragma unroll
  for (int j = 1; j < NTN; ++j) { u64 o = p[j]; k = o < k ? o : k; }
  int idx = (int)(uint32_t)k;
  out[r] = gates[r] * att[r] * ((idx == *ecp) ? 1.0f : 0.0f);
}

extern "C" void kernel_launch(void* const* d_in, const int* in_sizes, int n_in,
                              void* d_out, int out_size, void* d_ws, size_t ws_size,
                              hipStream_t stream) {
  const float* X     = (const float*)d_in[0];
  const float* gates = (const float*)d_in[1];
  const float* att   = (const float*)d_in[2];
  const float* cent  = (const float*)d_in[3];
  const int*   ec    = (const int*)d_in[4];
  uint8_t* ws = (uint8_t*)d_ws;
  float* out = (float*)d_out;
  u64* partial = (u64*)(ws + PART_OFF);

  prep_centroids<<<K_CENT, 256, 0, stream>>>(cent, ws);
  cluster_gemm<<<(M_TOTAL / BM) * NTN, 256, 0, stream>>>(X, ws, partial);
  finalize<<<M_TOTAL / 256, 256, 0, stream>>>(partial, gates, att, ec, out);
}

// Round 6
// 490.489 us; speedup vs baseline: 1.0958x; 1.0899x over previous
//
#include <hip/hip_runtime.h>
#include <hip/hip_bf16.h>
#include <stdint.h>

typedef _Float16 half_t;
typedef __attribute__((ext_vector_type(8))) _Float16 half8;
typedef __attribute__((ext_vector_type(4))) _Float16 half4v;
typedef __attribute__((ext_vector_type(4))) float float4v;
typedef unsigned long long u64;

#define D_DIM 768
#define K_CENT 1024
#define M_TOTAL 65536
#define BM 256
#define BN 256
#define BK 32
#define NT 24      /* 768/32 K-tiles */
#define NTN 4      /* 1024/256 n-tiles */

#define BPLANE 16384u  /* one hi or lo plane per chunk: 256 rows x 64 B */

/* ws layout (bytes):
   [0, 1.5MB)       Chi: pre-swizzled f16 hi tiles, [n_tile(4)][chunk(24)][16KB]
   [1.5MB, 3MB)     Clo: lo tiles, same layout
   [3MB, +4KB)      c2[1024] fp32
   [3MB+8KB, +2MB)  partial u64 [65536][4]                                  */
#define CLO_OFF  (NTN * NT * BPLANE)   /* 1.5 MB */
#define C2_OFF   (2u * CLO_OFF)        /* 3 MB */
#define PART_OFF (C2_OFF + 8192u)

/* LDS map (128 KB dynamic):
   Abuf[c] @ c*32768        (hi 16K | lo 16K)
   Bbuf[c] @ 65536+c*32768  (hi 16K | lo 16K)                               */

// XOR swizzle for 64B row stride; rows r,r+8 alias 2-way (free). Verified 0
// bank conflicts in R1/R2.
__device__ __forceinline__ uint32_t swz(uint32_t row, uint32_t kbyte) {
  return (row * 64u + kbyte) ^ (((row >> 1) & 3u) << 4);
}

__device__ __forceinline__ void gll16(const void* g, void* l) {
  __builtin_amdgcn_global_load_lds((const __attribute__((address_space(1))) void*)g,
                                   (__attribute__((address_space(3))) void*)l,
                                   16, 0, 0);
}

// ---------------- kernel 1: centroid split + c2 ----------------
__global__ __launch_bounds__(256) void prep_centroids(const float* __restrict__ cent,
                                                      uint8_t* __restrict__ ws) {
  const int n = blockIdx.x;          // centroid 0..1023
  const int nt = n >> 8, row = n & 255;
  float ss = 0.f;
  for (int d = threadIdx.x; d < D_DIM; d += 256) {
    float a = cent[n * D_DIM + d];
    ss += a * a;
    half_t hi = (half_t)a;
    half_t lo = (half_t)(a - (float)hi);
    int chunk = d >> 5, k = d & 31;
    uint32_t off = (uint32_t)(nt * NT + chunk) * BPLANE + swz((uint32_t)row, (uint32_t)k * 2u);
    *(half_t*)(ws + off) = hi;
    *(half_t*)(ws + CLO_OFF + off) = lo;
  }
  for (int s = 32; s > 0; s >>= 1) ss += __shfl_down(ss, s, 64);
  __shared__ float red[4];
  if ((threadIdx.x & 63) == 0) red[threadIdx.x >> 6] = ss;
  __syncthreads();
  if (threadIdx.x == 0) {
    float* c2 = (float*)(ws + C2_OFF);
    c2[n] = red[0] + red[1] + red[2] + red[3];
  }
}

// ---------------- kernel 2: 256x256 4-phase split-f16 GEMM + argmin ----------------
__global__ __launch_bounds__(512, 2) void cluster_gemm(const float* __restrict__ X,
                                                       const uint8_t* __restrict__ wsro,
                                                       u64* __restrict__ partial) {
  extern __shared__ uint8_t smem[];

  // bijective XCD swizzle (1024%8==0): 4 consecutive L share one m-tile -> L2 A reuse
  const int bid = blockIdx.x;
  const int L = (bid & 7) * 128 + (bid >> 3);
  const int m_tile = L >> 2, n_tile = L & 3;
  const int m0 = m_tile * BM;

  const int tid = threadIdx.x;
  const int lane = tid & 63, w = tid >> 6;
  const int wm = w >> 2, wn = w & 3;          // 2M x 4N waves; wave tile 128x64
  const uint32_t kb = (uint32_t)((lane >> 4) << 4);

  const float* c2p = (const float*)(wsro + C2_OFF);
  const int ncol = n_tile * 256 + wn * 64 + (lane & 15);
  float c2v[4];
#pragma unroll
  for (int n = 0; n < 4; ++n) c2v[n] = c2p[ncol + n * 16];

  float4v acc[8][4];
#pragma unroll
  for (int m = 0; m < 8; ++m)
#pragma unroll
    for (int n = 0; n < 4; ++n) acc[m][n] = (float4v){0.f, 0.f, 0.f, 0.f};

  float4v apf[4];
  half8 ah[4], al[4], bh0[2], bl0[2], bh1[2], bl1[2];

#define A_LOAD(T1) { const int d0 = (T1) * BK;                                        \
  _Pragma("unroll") for (int i = 0; i < 4; ++i) {                                     \
    int f = tid + i * 512; int row = f >> 3, c4 = f & 7;                              \
    apf[i] = *(const float4v*)(X + (size_t)(m0 + row) * D_DIM + d0 + c4 * 4); } }

#define A_WRITE(DB) { _Pragma("unroll") for (int i = 0; i < 4; ++i) {                 \
    int f = tid + i * 512; int row = f >> 3, c4 = f & 7;                              \
    half4v hi, lo;                                                                    \
    _Pragma("unroll") for (int j = 0; j < 4; ++j) {                                   \
      half_t h = (half_t)apf[i][j]; hi[j] = h; lo[j] = (half_t)(apf[i][j] - (float)h);} \
    uint32_t a = (DB) + swz((uint32_t)row, (uint32_t)c4 * 8u);                        \
    *(half4v*)(smem + a) = hi; *(half4v*)(smem + a + 16384u) = lo; } }

#define B_GLL_HI(T1, DB) { const uint8_t* s_ = wsro + (uint32_t)(n_tile * NT + (T1)) * BPLANE; \
    uint32_t o_ = (uint32_t)w * 2048u;                                                \
    gll16(s_ + o_ + (lane << 4), smem + (DB) + o_);                                   \
    gll16(s_ + o_ + 1024u + (lane << 4), smem + (DB) + o_ + 1024u); }

#define B_GLL_LO(T1, DB) { const uint8_t* s_ = wsro + CLO_OFF + (uint32_t)(n_tile * NT + (T1)) * BPLANE; \
    uint32_t o_ = (uint32_t)w * 2048u;                                                \
    gll16(s_ + o_ + (lane << 4), smem + (DB) + 16384u + o_);                          \
    gll16(s_ + o_ + 1024u + (lane << 4), smem + (DB) + 16384u + o_ + 1024u); }

#define READ_A(HALF, AB) { _Pragma("unroll") for (int m = 0; m < 4; ++m) {            \
    uint32_t a = (AB) + swz((uint32_t)(wm * 128 + ((HALF) * 4 + m) * 16 + (lane & 15)), kb); \
    ah[m] = *(const half8*)(smem + a); al[m] = *(const half8*)(smem + a + 16384u); } }

#define READ_B(NH, BB, BH, BL) { _Pragma("unroll") for (int n = 0; n < 2; ++n) {      \
    uint32_t a = (BB) + swz((uint32_t)(wn * 64 + ((NH) * 2 + n) * 16 + (lane & 15)), kb); \
    BH[n] = *(const half8*)(smem + a); BL[n] = *(const half8*)(smem + a + 16384u); } }

#define MFMA_Q(MB, NB, BH, BL) { __builtin_amdgcn_s_setprio(1);                       \
  _Pragma("unroll") for (int m = 0; m < 4; ++m)                                       \
  _Pragma("unroll") for (int n = 0; n < 2; ++n) {                                     \
    float4v* A_ = &acc[(MB) + m][(NB) + n];                                           \
    *A_ = __builtin_amdgcn_mfma_f32_16x16x32_f16(ah[m], BH[n], *A_, 0, 0, 0);         \
    *A_ = __builtin_amdgcn_mfma_f32_16x16x32_f16(ah[m], BL[n], *A_, 0, 0, 0);         \
    *A_ = __builtin_amdgcn_mfma_f32_16x16x32_f16(al[m], BH[n], *A_, 0, 0, 0); }       \
  __builtin_amdgcn_s_setprio(0); }

#define BAR() __builtin_amdgcn_s_barrier()

  uint32_t Ab = 0u, Bb = 65536u;

  // ---- prologue: stage tile 0 ----
  A_LOAD(0);
  B_GLL_HI(0, Bb); B_GLL_LO(0, Bb);
  A_WRITE(Ab);                                    // compiler waits vmcnt for apf
  asm volatile("s_waitcnt vmcnt(0) lgkmcnt(0)" ::: "memory");
  BAR();

  for (int t = 0; t < NT; ++t) {
    const uint32_t AbN = Ab ^ 32768u, BbN = Bb ^ 32768u;
    const bool st = (t + 1 < NT);
    // P1: reads A-half0 + B-half0 ; issue A(t+1) loads + B hi gll
    if (st) { A_LOAD(t + 1); B_GLL_HI(t + 1, BbN); }
    READ_A(0, Ab);
    READ_B(0, Bb, bh0, bl0);
    BAR();
    MFMA_Q(0, 0, bh0, bl0);
    BAR();
    // P2: reads B-half1 ; B lo gll
    if (st) { B_GLL_LO(t + 1, BbN); }
    READ_B(1, Bb, bh1, bl1);
    BAR();
    MFMA_Q(0, 2, bh1, bl1);
    BAR();
    // P3: reads A-half1
    READ_A(1, Ab);
    BAR();
    MFMA_Q(4, 2, bh1, bl1);
    BAR();
    // P4: convert+write A(t+1) ; last quadrant ; single drain per K-tile
    if (st) { A_WRITE(AbN); }                     // compiler vmcnt(4): apf ready, gll stays
    MFMA_Q(4, 0, bh0, bl0);
    asm volatile("s_waitcnt vmcnt(0) lgkmcnt(0)" ::: "memory");  // gll issued >=2 phases ago: ~free
    BAR();
    Ab = AbN; Bb = BbN;
  }

  // ---- epilogue: score = c2 - 2*dot ; per-row argmin over this n-tile ----
  u64* scratch = (u64*)smem;                      // Abuf0 region; safe after final BAR
  const int g = lane >> 4;
#pragma unroll
  for (int m = 0; m < 8; ++m) {
#pragma unroll
    for (int r = 0; r < 4; ++r) {
      u64 key = ~0ull;
#pragma unroll
      for (int n = 0; n < 4; ++n) {
        float s = c2v[n] - 2.0f * acc[m][n][r];
        uint32_t ub = __float_as_uint(s);
        ub ^= (uint32_t)((int32_t)ub >> 31) | 0x80000000u;   // order-preserving flip
        u64 cand = ((u64)ub << 32) | (uint32_t)(ncol + n * 16);
        key = cand < key ? cand : key;
      }
#pragma unroll
      for (int d = 1; d < 16; d <<= 1) {
        u64 o = __shfl_xor(key, d, 64);
        key = o < key ? o : key;
      }
      if ((lane & 15) == 0) {
        int row = wm * 128 + m * 16 + g * 4 + r;
        scratch[row * 4 + wn] = key;
      }
    }
  }
  __syncthreads();
  if (tid < 256) {
    u64 k = scratch[tid * 4];
#pragma unroll
    for (int j = 1; j < 4; ++j) { u64 o = scratch[tid * 4 + j]; k = o < k ? o : k; }
    partial[(size_t)(m0 + tid) * NTN + n_tile] = k;
  }
}

// ---------------- kernel 3: combine partials -> output ----------------
__global__ __launch_bounds__(256) void finalize(const u64* __restrict__ partial,
                                                const float* __restrict__ gates,
                                                const float* __restrict__ att,
                                                const int* __restrict__ ecp,
                                                float* __restrict__ out) {
  int r = blockIdx.x * 256 + threadIdx.x;
  const u64* p = partial + (size_t)r * NTN;
  u64 k = p[0];
#pragma unroll
  for (int j = 1; j < NTN; ++j) { u64 o = p[j]; k = o < k ? o : k; }
  int idx = (int)(uint32_t)k;
  out[r] = gates[r] * att[r] * ((idx == *ecp) ? 1.0f : 0.0f);
}

extern "C" void kernel_launch(void* const* d_in, const int* in_sizes, int n_in,
                              void* d_out, int out_size, void* d_ws, size_t ws_size,
                              hipStream_t stream) {
  const float* X     = (const float*)d_in[0];
  const float* gates = (const float*)d_in[1];
  const float* att   = (const float*)d_in[2];
  const float* cent  = (const float*)d_in[3];
  const int*   ec    = (const int*)d_in[4];
  uint8_t* ws = (uint8_t*)d_ws;
  float* out = (float*)d_out;
  u64* partial = (u64*)(ws + PART_OFF);

  hipFuncSetAttribute((const void*)cluster_gemm,
                      hipFuncAttributeMaxDynamicSharedMemorySize, 131072);

  prep_centroids<<<K_CENT, 256, 0, stream>>>(cent, ws);
  cluster_gemm<<<(M_TOTAL / BM) * NTN, 512, 131072, stream>>>(X, ws, partial);
  finalize<<<M_TOTAL / 256, 256, 0, stream>>>(partial, gates, att, ec, out);
}